// Round 14
// baseline (1071.286 us; speedup 1.0000x reference)
//
#include <hip/hip_runtime.h>
#include <hip/hip_fp16.h>
#include <math.h>

#define N_NODES 50000
#define E_EDGES 800000
#define ETOT    (E_EDGES + N_NODES)

// bucketed scatter params
#define BUCK_SHIFT 9
#define BUCK_SZ   (1 << BUCK_SHIFT)                               // 512
#define NBUCK ((N_NODES + BUCK_SZ - 1) >> BUCK_SHIFT)             // 98
#define BS_EPT 16
#define BS_THREADS 256
#define BS_EPB (BS_THREADS * BS_EPT)                              // 4096
#define BS_NBLK ((ETOT + BS_EPB - 1) / BS_EPB)

// gemm0 grid / hist slice
#define GEMM0_GRID ((N_NODES + 63) / 64)                          // 782
#define HPB ((ETOT + GEMM0_GRID - 1) / GEMM0_GRID)                // 1088

// bucket-agg: 8 slices of 64 nodes per 512-node bucket
#define AGG_GRID (NBUCK * 8)                                      // 784
#define LIST_CAP 1600    // slice edge count ~Binom mean 1088, sd 33; 15.5 sd margin

// ---------------------------------------------------------------------------
// Layer-0 GEMM + alpha + fused hist (r13: no X staging, W in LDS).
// ---------------------------------------------------------------------------
__global__ __launch_bounds__(256)
void gemm0_hist_kernel(const float* __restrict__ X, const float* __restrict__ W,
                       const float* __restrict__ a_s, const float* __restrict__ a_d,
                       const int* __restrict__ ei, int* __restrict__ bcnt,
                       __half* __restrict__ H16, float* __restrict__ asrc,
                       float* __restrict__ adst)
{
    constexpr int DIN = 128, DOUT = 64;
    constexpr int COLG = DOUT / 4;     // 16

    __shared__ float Wl[DIN * DOUT];   // 32 KB
    __shared__ int   lh[NBUCK];

    const int tid = threadIdx.x;
    const int row0b = blockIdx.x * 64;

    for (int i = tid; i < DIN * DOUT / 4; i += 256)
        ((float4*)Wl)[i] = ((const float4*)W)[i];
    __syncthreads();

    const int tx = tid % COLG;
    const int ty = tid / COLG;
    const int r0 = ty * 4;
    const int c0 = tx * 4;

    const float* Xr[4];
#pragma unroll
    for (int i = 0; i < 4; ++i) {
        int gr = row0b + r0 + i;
        Xr[i] = X + (size_t)min(gr, N_NODES - 1) * DIN;
    }

    float acc[4][4] = {};
#pragma unroll 4
    for (int kk = 0; kk < DIN; kk += 4) {
        float a[4][4], w[4][4];
#pragma unroll
        for (int i = 0; i < 4; ++i)
            *(float4*)a[i] = *(const float4*)&Xr[i][kk];
#pragma unroll
        for (int j = 0; j < 4; ++j)
            *(float4*)w[j] = *(const float4*)&Wl[(kk + j) * DOUT + c0];
#pragma unroll
        for (int i = 0; i < 4; ++i)
#pragma unroll
            for (int j = 0; j < 4; ++j)
                acc[i][j] = fmaf(a[i][0], w[0][j],
                            fmaf(a[i][1], w[1][j],
                            fmaf(a[i][2], w[2][j],
                            fmaf(a[i][3], w[3][j], acc[i][j]))));
    }

    float as4[4], ad4[4];
    *(float4*)as4 = *(const float4*)&a_s[c0];
    *(float4*)ad4 = *(const float4*)&a_d[c0];

#pragma unroll
    for (int i = 0; i < 4; ++i) {
        const int gr = row0b + r0 + i;
        float ps = acc[i][0] * as4[0] + acc[i][1] * as4[1] +
                   acc[i][2] * as4[2] + acc[i][3] * as4[3];
        float pd = acc[i][0] * ad4[0] + acc[i][1] * ad4[1] +
                   acc[i][2] * ad4[2] + acc[i][3] * ad4[3];
#pragma unroll
        for (int off = COLG / 2; off >= 1; off >>= 1) {
            ps += __shfl_xor(ps, off, 64);
            pd += __shfl_xor(pd, off, 64);
        }
        if (gr < N_NODES) {
            __half2 p01 = __floats2half2_rn(acc[i][0], acc[i][1]);
            __half2 p23 = __floats2half2_rn(acc[i][2], acc[i][3]);
            uint2 pk;
            pk.x = *(unsigned int*)&p01;
            pk.y = *(unsigned int*)&p23;
            *(uint2*)&H16[gr * DOUT + c0] = pk;
            if (tx == 0) { asrc[gr] = ps; adst[gr] = pd; }
        }
    }

    // ---- fused hist ----
    for (int i = tid; i < NBUCK; i += 256) lh[i] = 0;
    __syncthreads();
    const int h0 = blockIdx.x * HPB;
    const int hend = min(h0 + HPB, ETOT);
    for (int eid = h0 + tid; eid < hend; eid += 256) {
        int dst = (eid < E_EDGES) ? ei[E_EDGES + eid] : (eid - E_EDGES);
        atomicAdd(&lh[dst >> BUCK_SHIFT], 1);
    }
    __syncthreads();
    for (int i = tid; i < NBUCK; i += 256)
        if (lh[i] > 0) atomicAdd(&bcnt[i], lh[i]);
}

// ---------------------------------------------------------------------------
// Generic GEMM + alpha (layers 1,2) — no X staging, W in LDS (r13-verified).
// ---------------------------------------------------------------------------
template<int DIN, int DOUT>
__global__ __launch_bounds__(256)
void gemm_alpha_kernel(const float* __restrict__ X, const float* __restrict__ W,
                       const float* __restrict__ a_s, const float* __restrict__ a_d,
                       __half* __restrict__ H16, float* __restrict__ asrc,
                       float* __restrict__ adst)
{
    constexpr int COLG = DOUT / 4;
    constexpr int ROWG = 256 / COLG;
    constexpr int BM   = ROWG * 4;

    __shared__ float Wl[DIN * DOUT];

    const int tid = threadIdx.x;
    const int row0b = blockIdx.x * BM;

    for (int i = tid; i < DIN * DOUT / 4; i += 256)
        ((float4*)Wl)[i] = ((const float4*)W)[i];
    __syncthreads();

    const int tx = tid % COLG;
    const int ty = tid / COLG;
    const int r0 = ty * 4;
    const int c0 = tx * 4;

    const float* Xr[4];
#pragma unroll
    for (int i = 0; i < 4; ++i) {
        int gr = row0b + r0 + i;
        Xr[i] = X + (size_t)min(gr, N_NODES - 1) * DIN;
    }

    float acc[4][4] = {};
#pragma unroll 4
    for (int kk = 0; kk < DIN; kk += 4) {
        float a[4][4], w[4][4];
#pragma unroll
        for (int i = 0; i < 4; ++i)
            *(float4*)a[i] = *(const float4*)&Xr[i][kk];
#pragma unroll
        for (int j = 0; j < 4; ++j)
            *(float4*)w[j] = *(const float4*)&Wl[(kk + j) * DOUT + c0];
#pragma unroll
        for (int i = 0; i < 4; ++i)
#pragma unroll
            for (int j = 0; j < 4; ++j)
                acc[i][j] = fmaf(a[i][0], w[0][j],
                            fmaf(a[i][1], w[1][j],
                            fmaf(a[i][2], w[2][j],
                            fmaf(a[i][3], w[3][j], acc[i][j]))));
    }

    float as4[4], ad4[4];
    *(float4*)as4 = *(const float4*)&a_s[c0];
    *(float4*)ad4 = *(const float4*)&a_d[c0];

#pragma unroll
    for (int i = 0; i < 4; ++i) {
        const int gr = row0b + r0 + i;
        float ps = acc[i][0] * as4[0] + acc[i][1] * as4[1] +
                   acc[i][2] * as4[2] + acc[i][3] * as4[3];
        float pd = acc[i][0] * ad4[0] + acc[i][1] * ad4[1] +
                   acc[i][2] * ad4[2] + acc[i][3] * ad4[3];
#pragma unroll
        for (int off = COLG / 2; off >= 1; off >>= 1) {
            ps += __shfl_xor(ps, off, 64);
            pd += __shfl_xor(pd, off, 64);
        }
        if (gr < N_NODES) {
            __half2 p01 = __floats2half2_rn(acc[i][0], acc[i][1]);
            __half2 p23 = __floats2half2_rn(acc[i][2], acc[i][3]);
            uint2 pk;
            pk.x = *(unsigned int*)&p01;
            pk.y = *(unsigned int*)&p23;
            *(uint2*)&H16[gr * DOUT + c0] = pk;
            if (tx == 0) { asrc[gr] = ps; adst[gr] = pd; }
        }
    }
}

// ---------------------------------------------------------------------------
// binscatter with LOCAL scan of bcnt (r13-verified). cur[] zero-initialized.
// ---------------------------------------------------------------------------
__global__ __launch_bounds__(BS_THREADS)
void binscatter_kernel(const int* __restrict__ ei, const int* __restrict__ bcnt,
                       int* __restrict__ cur, unsigned int* __restrict__ tmp)
{
    __shared__ int lcnt[NBUCK];
    __shared__ int lbase[NBUCK];
    __shared__ int lscan[128];
    const int t = threadIdx.x;

    if (t < 128) {
        const int v = (t < NBUCK) ? bcnt[t] : 0;
        lscan[t] = v;
        __syncthreads();
        for (int off = 1; off < 128; off <<= 1) {
            int u = (t >= off) ? lscan[t - off] : 0;
            __syncthreads();
            lscan[t] += u;
            __syncthreads();
        }
        if (t < NBUCK) lbase[t] = lscan[t] - v;
    } else {
        __syncthreads();
        for (int off = 1; off < 128; off <<= 1) { __syncthreads(); __syncthreads(); }
    }
    for (int i = t; i < NBUCK; i += BS_THREADS) lcnt[i] = 0;
    __syncthreads();

    const int e0 = blockIdx.x * BS_EPB;
    unsigned int pk[BS_EPT];
    int rk[BS_EPT];
    int bk[BS_EPT];
#pragma unroll
    for (int k = 0; k < BS_EPT; ++k) {
        const int eid = e0 + k * BS_THREADS + t;
        bk[k] = -1;
        if (eid < ETOT) {
            int src, dst;
            if (eid < E_EDGES) { src = ei[eid]; dst = ei[E_EDGES + eid]; }
            else               { src = dst = eid - E_EDGES; }
            bk[k] = dst >> BUCK_SHIFT;
            pk[k] = ((unsigned int)dst << 16) | (unsigned int)src;
            rk[k] = atomicAdd(&lcnt[bk[k]], 1);
        }
    }
    __syncthreads();
    for (int i = t; i < NBUCK; i += BS_THREADS)
        if (lcnt[i] > 0) lbase[i] += atomicAdd(&cur[i], lcnt[i]);
    __syncthreads();
#pragma unroll
    for (int k = 0; k < BS_EPT; ++k)
        if (bk[k] >= 0) tmp[lbase[bk[k]] + rk[k]] = pk[k];
}

// ---------------------------------------------------------------------------
// bucket_agg: aggregate a 64-node slice directly from bucket-clustered tmp.
// Phase A: coalesced scan + slice filter + score-once + LDS compaction.
// Phase B: dense 8x8 (or 16x4) edge x feat-lane pass, fp16 row gathers,
//          LDS float atomics into acc[64][DOUT+1].
// Phase C: normalize + bias + activation, coalesced store.
// ---------------------------------------------------------------------------
template<int DOUT, int ACT>
__global__ __launch_bounds__(256)
void bucket_agg_kernel(const unsigned int* __restrict__ tmp,
                       const int* __restrict__ bcnt,
                       const float* __restrict__ asrc,
                       const float* __restrict__ adst,
                       const __half* __restrict__ H16,
                       const float* __restrict__ bias,
                       float* __restrict__ out)
{
    constexpr int FL    = DOUT / 8;    // 8 (dout=64) or 4 (dout=32)
    constexpr int SLOTS = 64 / FL;     // 8 or 16 edges per wave-iter
    constexpr int AW    = DOUT + 1;    // acc row width (feats + s)

    __shared__ float accL[64 * AW];
    __shared__ unsigned int lpk[LIST_CAP];
    __shared__ float lp[LIST_CAP];
    __shared__ float adl[64];
    __shared__ int lscan[128];
    __shared__ int sbase, scnt, ln;

    const int t = threadIdx.x;
    const int bucket = blockIdx.x >> 3;
    const int slice  = blockIdx.x & 7;
    const int node0  = (bucket << BUCK_SHIFT) + slice * 64;

    // bucket base via local 128-wide scan of bcnt
    if (t < 128) lscan[t] = (t < NBUCK) ? bcnt[t] : 0;
    __syncthreads();
    for (int off = 1; off < 128; off <<= 1) {
        int u = (t >= off && t < 128) ? lscan[t - off] : 0;
        __syncthreads();
        if (t < 128) lscan[t] += u;
        __syncthreads();
    }
    if (t == 0) {
        sbase = lscan[bucket] - bcnt[bucket];
        scnt  = bcnt[bucket];
        ln    = 0;
    }
    for (int i = t; i < 64 * AW; i += 256) accL[i] = 0.f;
    if (t < 64) {
        int g = node0 + t;
        adl[t] = (g < N_NODES) ? adst[g] : 0.f;
    }
    __syncthreads();
    const int base = sbase, cnt = scnt;

    // ---- phase A: filter + score-once + compact ----
    for (int i = t; i < cnt; i += 256) {
        const unsigned int pk = tmp[base + i];
        const unsigned int dst = pk >> 16;
        if (((dst >> 6) & 7u) == (unsigned)slice) {
            const int ldst = dst & 63;
            float v = asrc[pk & 0xffffu] + adl[ldst];
            v = fmaxf(v, 0.2f * v);
            const float p = __expf(fminf(v, 80.f));
            const int pos = atomicAdd(&ln, 1);
            if (pos < LIST_CAP) {
                lpk[pos] = ((unsigned)ldst << 16) | (pk & 0xffffu);
                lp[pos]  = p;
            }
        }
    }
    __syncthreads();
    const int n = min(ln, LIST_CAP);

    // ---- phase B: dense accumulation ----
    const int lane = t & 63;
    const int fl   = lane % FL;
    const int slot = lane / FL;
    const int wv   = t >> 6;
    const __half* __restrict__ Hf = H16 + fl * 8;

    for (int e0 = wv * SLOTS; e0 < n; e0 += 4 * SLOTS) {
        const int e = e0 + slot;
        if (e < n) {
            const unsigned int pk = lpk[e];
            const float p = lp[e];
            const unsigned int src = pk & 0xffffu;
            const int ldst = pk >> 16;
            const uint4 h = *(const uint4*)(Hf + src * DOUT);
            const float2 f0 = __half22float2(*(const __half2*)&h.x);
            const float2 f1 = __half22float2(*(const __half2*)&h.y);
            const float2 f2 = __half22float2(*(const __half2*)&h.z);
            const float2 f3 = __half22float2(*(const __half2*)&h.w);
            float* a = &accL[ldst * AW + fl * 8];
            atomicAdd(a + 0, p * f0.x);
            atomicAdd(a + 1, p * f0.y);
            atomicAdd(a + 2, p * f1.x);
            atomicAdd(a + 3, p * f1.y);
            atomicAdd(a + 4, p * f2.x);
            atomicAdd(a + 5, p * f2.y);
            atomicAdd(a + 6, p * f3.x);
            atomicAdd(a + 7, p * f3.y);
            if (fl == 0) atomicAdd(&accL[ldst * AW + DOUT], p);
        }
    }
    __syncthreads();

    // ---- phase C: normalize + bias + act, coalesced store ----
    for (int i = t; i < 64 * DOUT; i += 256) {
        const int nn = i / DOUT, f = i % DOUT;
        const int g = node0 + nn;
        if (g < N_NODES) {
            const float s = accL[nn * AW + DOUT];
            float v = accL[nn * AW + f] / s + bias[f];
            out[g * DOUT + f] = (ACT == 0) ? fmaxf(v, 0.f) : tanhf(v);
        }
    }
}

// ---------------------------------------------------------------------------

extern "C" void kernel_launch(void* const* d_in, const int* in_sizes, int n_in,
                              void* d_out, int out_size, void* d_ws, size_t ws_size,
                              hipStream_t stream)
{
    const float* x  = (const float*)d_in[0];
    const int*   ei = (const int*)d_in[1];
    const float* W0 = (const float*)d_in[2];
    const float* as0= (const float*)d_in[3];
    const float* ad0= (const float*)d_in[4];
    const float* b0 = (const float*)d_in[5];
    const float* W1 = (const float*)d_in[6];
    const float* as1= (const float*)d_in[7];
    const float* ad1= (const float*)d_in[8];
    const float* b1 = (const float*)d_in[9];
    const float* W2 = (const float*)d_in[10];
    const float* as2= (const float*)d_in[11];
    const float* ad2= (const float*)d_in[12];
    const float* b2 = (const float*)d_in[13];
    float* out = (float*)d_out;

    char* wsb = (char*)d_ws;
    auto take = [&](size_t bytes) {
        char* p = wsb;
        wsb += (bytes + 255) & ~size_t(255);
        return p;
    };
    __half* h16    = (__half*)take(sizeof(__half) * N_NODES * 64);
    float* buf_act = (float*)take(sizeof(float) * N_NODES * 64);
    float* asrc    = (float*)take(sizeof(float) * N_NODES);
    float* adst    = (float*)take(sizeof(float) * N_NODES);
    int*   bc      = (int*)take(sizeof(int) * NBUCK * 2);   // bcnt | cur
    int*   bcnt    = bc;
    int*   cur     = bc + NBUCK;
    unsigned int* tmp = (unsigned int*)take(sizeof(unsigned int) * ETOT);

    hipMemsetAsync(bc, 0, sizeof(int) * NBUCK * 2, stream);

    // layer-0 gemm + alpha + fused edge-bucket histogram
    gemm0_hist_kernel<<<GEMM0_GRID, 256, 0, stream>>>(
        x, W0, as0, ad0, ei, bcnt, h16, asrc, adst);

    // bucket-clustered edge list (consumed directly by bucket_agg; no sort)
    binscatter_kernel<<<BS_NBLK, BS_THREADS, 0, stream>>>(ei, bcnt, cur, tmp);

    // layer 0 aggregation (relu)
    bucket_agg_kernel<64, 0><<<AGG_GRID, 256, 0, stream>>>(
        tmp, bcnt, asrc, adst, h16, b0, buf_act);

    // layer 1
    gemm_alpha_kernel<64, 64><<<GEMM0_GRID, 256, 0, stream>>>(
        buf_act, W1, as1, ad1, h16, asrc, adst);
    bucket_agg_kernel<64, 0><<<AGG_GRID, 256, 0, stream>>>(
        tmp, bcnt, asrc, adst, h16, b1, buf_act);

    // layer 2
    gemm_alpha_kernel<64, 32><<<(N_NODES + 127) / 128, 256, 0, stream>>>(
        buf_act, W2, as2, ad2, h16, asrc, adst);
    bucket_agg_kernel<32, 1><<<AGG_GRID, 256, 0, stream>>>(
        tmp, bcnt, asrc, adst, h16, b2, out);
}

// Round 15
// 184.325 us; speedup vs baseline: 5.8119x; 5.8119x over previous
//
#include <hip/hip_runtime.h>
#include <hip/hip_fp16.h>
#include <math.h>

#define N_NODES 50000
#define E_EDGES 800000
#define ETOT    (E_EDGES + N_NODES)

// bucketed scatter params
#define BUCK_SHIFT 9
#define BUCK_SZ   (1 << BUCK_SHIFT)                               // 512
#define NBUCK ((N_NODES + BUCK_SZ - 1) >> BUCK_SHIFT)             // 98
#define BS_EPT 16
#define BS_THREADS 256
#define BS_EPB (BS_THREADS * BS_EPT)                              // 4096
#define BS_NBLK ((ETOT + BS_EPB - 1) / BS_EPB)

// ---------------------------------------------------------------------------
// Register-tiled GEMM + alpha epilogue. H written as fp16 (gather payload).
// ---------------------------------------------------------------------------
template<int DIN, int DOUT>
__global__ __launch_bounds__(256)
void gemm_alpha_kernel(const float* __restrict__ X, const float* __restrict__ W,
                       const float* __restrict__ a_s, const float* __restrict__ a_d,
                       __half* __restrict__ H16, float* __restrict__ asrc,
                       float* __restrict__ adst)
{
    constexpr int COLG = DOUT / 4;
    constexpr int ROWG = 256 / COLG;
    constexpr int BM   = ROWG * 4;
    constexpr int K4   = DIN / 4;

    __shared__ float Xl[BM * DIN];
    __shared__ float Wl[DIN * DOUT];

    const int tid = threadIdx.x;
    const int row0b = blockIdx.x * BM;

    for (int i = tid; i < DIN * DOUT / 4; i += 256)
        ((float4*)Wl)[i] = ((const float4*)W)[i];

    for (int i = tid; i < BM * K4; i += 256) {
        int r  = i / K4;
        int j  = i % K4;
        int gr = row0b + r;
        float4 v = make_float4(0.f, 0.f, 0.f, 0.f);
        if (gr < N_NODES) v = ((const float4*)X)[gr * K4 + j];
        *(float4*)&Xl[r * DIN + ((j ^ ((r >> 2) & 7)) << 2)] = v;
    }
    __syncthreads();

    const int tx = tid % COLG;
    const int ty = tid / COLG;
    const int r0 = ty * 4;
    const int c0 = tx * 4;
    const int swz = ty & 7;

    float acc[4][4] = {};
    for (int kk = 0; kk < DIN; kk += 4) {
        float a[4][4], w[4][4];
        const int jk = ((kk >> 2) ^ swz) << 2;
#pragma unroll
        for (int i = 0; i < 4; ++i)
            *(float4*)a[i] = *(const float4*)&Xl[(r0 + i) * DIN + jk];
#pragma unroll
        for (int j = 0; j < 4; ++j)
            *(float4*)w[j] = *(const float4*)&Wl[(kk + j) * DOUT + c0];
#pragma unroll
        for (int i = 0; i < 4; ++i)
#pragma unroll
            for (int j = 0; j < 4; ++j)
                acc[i][j] = fmaf(a[i][0], w[0][j],
                            fmaf(a[i][1], w[1][j],
                            fmaf(a[i][2], w[2][j],
                            fmaf(a[i][3], w[3][j], acc[i][j]))));
    }

    float as4[4], ad4[4];
    *(float4*)as4 = *(const float4*)&a_s[c0];
    *(float4*)ad4 = *(const float4*)&a_d[c0];

#pragma unroll
    for (int i = 0; i < 4; ++i) {
        const int gr = row0b + r0 + i;
        float ps = acc[i][0] * as4[0] + acc[i][1] * as4[1] +
                   acc[i][2] * as4[2] + acc[i][3] * as4[3];
        float pd = acc[i][0] * ad4[0] + acc[i][1] * ad4[1] +
                   acc[i][2] * ad4[2] + acc[i][3] * ad4[3];
#pragma unroll
        for (int off = COLG / 2; off >= 1; off >>= 1) {
            ps += __shfl_xor(ps, off, 64);
            pd += __shfl_xor(pd, off, 64);
        }
        if (gr < N_NODES) {
            __half2 p01 = __floats2half2_rn(acc[i][0], acc[i][1]);
            __half2 p23 = __floats2half2_rn(acc[i][2], acc[i][3]);
            uint2 pk;
            pk.x = *(unsigned int*)&p01;
            pk.y = *(unsigned int*)&p23;
            *(uint2*)&H16[gr * DOUT + c0] = pk;
            if (tx == 0) { asrc[gr] = ps; adst[gr] = pd; }
        }
    }
}

// ---------------------------------------------------------------------------
// CSR build: zero98 -> hist -> scan98 -> binscatter -> bucket_sort
// (round-8/10 pipeline: separate kernels keep each phase at full parallelism)
// ---------------------------------------------------------------------------
__global__ __launch_bounds__(128)
void zero98_kernel(int* __restrict__ bcnt)
{
    int i = threadIdx.x;
    if (i < NBUCK) bcnt[i] = 0;
}

__global__ __launch_bounds__(BS_THREADS)
void hist_kernel(const int* __restrict__ ei, int* __restrict__ bcnt)
{
    __shared__ int lcnt[NBUCK];
    const int t = threadIdx.x;
    for (int i = t; i < NBUCK; i += BS_THREADS) lcnt[i] = 0;
    __syncthreads();
    const int e0 = blockIdx.x * BS_EPB;
#pragma unroll
    for (int k = 0; k < BS_EPT; ++k) {
        const int eid = e0 + k * BS_THREADS + t;
        if (eid < ETOT) {
            int dst = (eid < E_EDGES) ? ei[E_EDGES + eid] : (eid - E_EDGES);
            atomicAdd(&lcnt[dst >> BUCK_SHIFT], 1);
        }
    }
    __syncthreads();
    for (int i = t; i < NBUCK; i += BS_THREADS)
        if (lcnt[i] > 0) atomicAdd(&bcnt[i], lcnt[i]);
}

__global__ __launch_bounds__(128)
void scan98_kernel(const int* __restrict__ bcnt, int* __restrict__ cur,
                   int* __restrict__ cur0)
{
    __shared__ int lds[128];
    const int t = threadIdx.x;
    const int v = (t < NBUCK) ? bcnt[t] : 0;
    lds[t] = v;
    __syncthreads();
    for (int off = 1; off < 128; off <<= 1) {
        int u = (t >= off) ? lds[t - off] : 0;
        __syncthreads();
        lds[t] += u;
        __syncthreads();
    }
    if (t < NBUCK) { cur[t] = lds[t] - v; cur0[t] = lds[t] - v; }
}

__global__ __launch_bounds__(BS_THREADS)
void binscatter_kernel(const int* __restrict__ ei, int* __restrict__ cur,
                       unsigned int* __restrict__ tmp)
{
    __shared__ int lcnt[NBUCK];
    __shared__ int lbase[NBUCK];
    const int t = threadIdx.x;
    for (int i = t; i < NBUCK; i += BS_THREADS) lcnt[i] = 0;
    __syncthreads();

    const int e0 = blockIdx.x * BS_EPB;
    unsigned int pk[BS_EPT];
    int rk[BS_EPT];
    int bk[BS_EPT];
#pragma unroll
    for (int k = 0; k < BS_EPT; ++k) {
        const int eid = e0 + k * BS_THREADS + t;
        bk[k] = -1;
        if (eid < ETOT) {
            int src, dst;
            if (eid < E_EDGES) { src = ei[eid]; dst = ei[E_EDGES + eid]; }
            else               { src = dst = eid - E_EDGES; }
            bk[k] = dst >> BUCK_SHIFT;
            pk[k] = ((unsigned int)dst << 16) | (unsigned int)src;
            rk[k] = atomicAdd(&lcnt[bk[k]], 1);
        }
    }
    __syncthreads();
    for (int i = t; i < NBUCK; i += BS_THREADS)
        if (lcnt[i] > 0) lbase[i] = atomicAdd(&cur[i], lcnt[i]);
    __syncthreads();
#pragma unroll
    for (int k = 0; k < BS_EPT; ++k)
        if (bk[k] >= 0) tmp[lbase[bk[k]] + rk[k]] = pk[k];
}

__global__ __launch_bounds__(BUCK_SZ)
void bucket_sort_kernel(const unsigned int* __restrict__ tmp,
                        const int* __restrict__ cur0,
                        const int* __restrict__ bcnt,
                        unsigned int* __restrict__ csr_pk,
                        int* __restrict__ offs)
{
    __shared__ int lcnt[BUCK_SZ];
    __shared__ int loff[BUCK_SZ];
    __shared__ int lcur[BUCK_SZ];
    const int bk = blockIdx.x;
    const int t  = threadIdx.x;
    const int base = cur0[bk];
    const int cnt  = bcnt[bk];

    lcnt[t] = 0;
    __syncthreads();
    for (int i = t; i < cnt; i += BUCK_SZ)
        atomicAdd(&lcnt[(tmp[base + i] >> 16) & (BUCK_SZ - 1)], 1);
    __syncthreads();

    const int v = lcnt[t];
    loff[t] = v;
    __syncthreads();
    for (int off = 1; off < BUCK_SZ; off <<= 1) {
        int u = (t >= off) ? loff[t - off] : 0;
        __syncthreads();
        loff[t] += u;
        __syncthreads();
    }
    const int excl = loff[t] - v;

    const int g = (bk << BUCK_SHIFT) + t;
    if (g <= N_NODES) offs[g] = base + excl;   // tail node writes offs[N]=ETOT

    lcur[t] = excl;
    __syncthreads();
    for (int i = t; i < cnt; i += BUCK_SZ) {
        const unsigned int pk = tmp[base + i];
        const int l = (pk >> 16) & (BUCK_SZ - 1);
        const int pos = atomicAdd(&lcur[l], 1);
        csr_pk[base + pos] = pk;
    }
}

// ---------------------------------------------------------------------------
// node_agg v5: inline edge score (FL-redundant), 16B fp16 gathers
// (8 H-rows in flight for DOUT=64), 1-deep csr_pk prefetch.
// wave = FL feature-lanes (8 feats each) x SLOTS edge-slots.
// ---------------------------------------------------------------------------
template<int DOUT, int ACT>
__global__ __launch_bounds__(256)
void node_agg_kernel(const int* __restrict__ offs,
                     const unsigned int* __restrict__ csr_pk,
                     const float* __restrict__ asrc,
                     const float* __restrict__ adst,
                     const __half* __restrict__ H16,
                     const float* __restrict__ b,
                     float* __restrict__ out)
{
    constexpr int FL    = DOUT / 8;    // 8 (dout=64) or 4 (dout=32)
    constexpr int SLOTS = 64 / FL;     // 8 or 16
    const int wv   = threadIdx.x >> 6;
    const int lane = threadIdx.x & 63;
    const int fl   = lane % FL;
    const int slot = lane / FL;
    const int node = blockIdx.x * 4 + wv;
    if (node >= N_NODES) return;

    const int beg = offs[node];
    const int end = offs[node + 1];
    const float adn = adst[node];
    const __half* __restrict__ Hf = H16 + fl * 8;

    float s = 0.f;
    float acc[8] = {};

    int eid = beg + slot;
    bool valid = (eid < end);
    unsigned int pk = valid ? csr_pk[eid] : 0u;

    for (int cb = beg; cb < end; cb += SLOTS) {
        const int nid = cb + SLOTS + slot;
        const bool nvalid = (nid < end);
        const unsigned int npk = nvalid ? csr_pk[nid] : 0u;

        float p = 0.f;
        uint4 h = make_uint4(0u, 0u, 0u, 0u);
        if (valid) {
            const unsigned int src = pk & 0xffffu;
            float v = asrc[src] + adn;
            v = fmaxf(v, 0.2f * v);
            p = __expf(fminf(v, 80.f));
            h = *(const uint4*)(Hf + src * DOUT);
        }
        const float2 f0 = __half22float2(*(const __half2*)&h.x);
        const float2 f1 = __half22float2(*(const __half2*)&h.y);
        const float2 f2 = __half22float2(*(const __half2*)&h.z);
        const float2 f3 = __half22float2(*(const __half2*)&h.w);
        s += p;
        acc[0] = fmaf(p, f0.x, acc[0]);
        acc[1] = fmaf(p, f0.y, acc[1]);
        acc[2] = fmaf(p, f1.x, acc[2]);
        acc[3] = fmaf(p, f1.y, acc[3]);
        acc[4] = fmaf(p, f2.x, acc[4]);
        acc[5] = fmaf(p, f2.y, acc[5]);
        acc[6] = fmaf(p, f3.x, acc[6]);
        acc[7] = fmaf(p, f3.y, acc[7]);
        valid = nvalid;
        pk = npk;
    }

    // reduce partial s/acc across slots
#pragma unroll
    for (int off = FL; off < 64; off <<= 1) {
        s += __shfl_xor(s, off, 64);
#pragma unroll
        for (int j = 0; j < 8; ++j)
            acc[j] += __shfl_xor(acc[j], off, 64);
    }

    if (slot == 0) {
        const float inv = 1.f / s;
        float o[8];
#pragma unroll
        for (int j = 0; j < 8; ++j) {
            float v = acc[j] * inv + b[fl * 8 + j];
            o[j] = (ACT == 0) ? fmaxf(v, 0.f) : tanhf(v);
        }
        *(float4*)&out[node * DOUT + fl * 8]     = *(float4*)&o[0];
        *(float4*)&out[node * DOUT + fl * 8 + 4] = *(float4*)&o[4];
    }
}

// ---------------------------------------------------------------------------

template<int DIN, int DOUT, int ACT>
static void run_layer(const float* X, const float* W, const float* a_s,
                      const float* a_d, const float* b,
                      const int* offs, const unsigned int* csr_pk,
                      __half* H16, float* asrc, float* adst,
                      float* out, hipStream_t stream)
{
    constexpr int COLG = DOUT / 4;
    constexpr int BM = (256 / COLG) * 4;
    const int gemm_grid = (N_NODES + BM - 1) / BM;
    gemm_alpha_kernel<DIN, DOUT><<<gemm_grid, 256, 0, stream>>>(
        X, W, a_s, a_d, H16, asrc, adst);

    const int agg_grid = (N_NODES + 3) / 4;
    node_agg_kernel<DOUT, ACT><<<agg_grid, 256, 0, stream>>>(
        offs, csr_pk, asrc, adst, H16, b, out);
}

extern "C" void kernel_launch(void* const* d_in, const int* in_sizes, int n_in,
                              void* d_out, int out_size, void* d_ws, size_t ws_size,
                              hipStream_t stream)
{
    const float* x  = (const float*)d_in[0];
    const int*   ei = (const int*)d_in[1];
    const float* W0 = (const float*)d_in[2];
    const float* as0= (const float*)d_in[3];
    const float* ad0= (const float*)d_in[4];
    const float* b0 = (const float*)d_in[5];
    const float* W1 = (const float*)d_in[6];
    const float* as1= (const float*)d_in[7];
    const float* ad1= (const float*)d_in[8];
    const float* b1 = (const float*)d_in[9];
    const float* W2 = (const float*)d_in[10];
    const float* as2= (const float*)d_in[11];
    const float* ad2= (const float*)d_in[12];
    const float* b2 = (const float*)d_in[13];
    float* out = (float*)d_out;

    char* wsb = (char*)d_ws;
    auto take = [&](size_t bytes) {
        char* p = wsb;
        wsb += (bytes + 255) & ~size_t(255);
        return p;
    };
    __half* h16    = (__half*)take(sizeof(__half) * N_NODES * 64);
    float* buf_act = (float*)take(sizeof(float) * N_NODES * 64);
    float* asrc    = (float*)take(sizeof(float) * N_NODES);
    float* adst    = (float*)take(sizeof(float) * N_NODES);
    int*   offs    = (int*)take(sizeof(int) * (N_NODES + 1));
    int*   bcnt    = (int*)take(sizeof(int) * NBUCK);
    int*   cur     = (int*)take(sizeof(int) * NBUCK);
    int*   cur0    = (int*)take(sizeof(int) * NBUCK);
    unsigned int* csr_pk = (unsigned int*)take(sizeof(unsigned int) * ETOT);
    // tmp aliases h16: dead before the first gemm writes H16
    unsigned int* tmp = (unsigned int*)h16;

    zero98_kernel<<<1, 128, 0, stream>>>(bcnt);
    hist_kernel<<<BS_NBLK, BS_THREADS, 0, stream>>>(ei, bcnt);
    scan98_kernel<<<1, 128, 0, stream>>>(bcnt, cur, cur0);
    binscatter_kernel<<<BS_NBLK, BS_THREADS, 0, stream>>>(ei, cur, tmp);
    bucket_sort_kernel<<<NBUCK, BUCK_SZ, 0, stream>>>(tmp, cur0, bcnt,
                                                      csr_pk, offs);

    run_layer<128, 64, 0>(x, W0, as0, ad0, b0, offs, csr_pk,
                          h16, asrc, adst, buf_act, stream);
    run_layer<64, 64, 0>(buf_act, W1, as1, ad1, b1, offs, csr_pk,
                         h16, asrc, adst, buf_act, stream);
    run_layer<64, 32, 1>(buf_act, W2, as2, ad2, b2, offs, csr_pk,
                         h16, asrc, adst, out, stream);
}

// Round 16
// 172.454 us; speedup vs baseline: 6.2120x; 1.0688x over previous
//
#include <hip/hip_runtime.h>
#include <hip/hip_fp16.h>
#include <math.h>

#define N_NODES 50000
#define E_EDGES 800000
#define ETOT    (E_EDGES + N_NODES)

// bucketed scatter params
#define BUCK_SHIFT 9
#define BUCK_SZ   (1 << BUCK_SHIFT)                               // 512
#define NBUCK ((N_NODES + BUCK_SZ - 1) >> BUCK_SHIFT)             // 98
#define BS_EPT 16
#define BS_THREADS 256
#define BS_EPB (BS_THREADS * BS_EPT)                              // 4096
#define BS_NBLK ((ETOT + BS_EPB - 1) / BS_EPB)                    // 208

#define GEMM0_GRID ((N_NODES + 63) / 64)                          // 782
#define PACK_GRID (GEMM0_GRID + BS_NBLK)                          // 990

// ---------------------------------------------------------------------------
// hist: per-block LDS bucket histogram -> global bcnt (r15-verified)
// ---------------------------------------------------------------------------
__global__ __launch_bounds__(BS_THREADS)
void hist_kernel(const int* __restrict__ ei, int* __restrict__ bcnt)
{
    __shared__ int lcnt[NBUCK];
    const int t = threadIdx.x;
    for (int i = t; i < NBUCK; i += BS_THREADS) lcnt[i] = 0;
    __syncthreads();
    const int e0 = blockIdx.x * BS_EPB;
#pragma unroll
    for (int k = 0; k < BS_EPT; ++k) {
        const int eid = e0 + k * BS_THREADS + t;
        if (eid < ETOT) {
            int dst = (eid < E_EDGES) ? ei[E_EDGES + eid] : (eid - E_EDGES);
            atomicAdd(&lcnt[dst >> BUCK_SHIFT], 1);
        }
    }
    __syncthreads();
    for (int i = t; i < NBUCK; i += BS_THREADS)
        if (lcnt[i] > 0) atomicAdd(&bcnt[i], lcnt[i]);
}

// ---------------------------------------------------------------------------
// PACKED: gemm0 (blocks 0..781) || binscatter (blocks 782..989).
// Each block runs ONE unchanged phase at its natural grid — true co-run,
// not the r9/r11 phase-serialization trap. Shared 32KB buffer is Wl for
// the gemm branch, scratch for the binscatter branch.
// ---------------------------------------------------------------------------
__global__ __launch_bounds__(256)
void gemm0_binscatter_kernel(const float* __restrict__ X,
                             const float* __restrict__ W,
                             const float* __restrict__ a_s,
                             const float* __restrict__ a_d,
                             __half* __restrict__ H16,
                             float* __restrict__ asrc,
                             float* __restrict__ adst,
                             const int* __restrict__ ei,
                             const int* __restrict__ bcnt,
                             int* __restrict__ cur,
                             unsigned int* __restrict__ tmp)
{
    __shared__ float smem[128 * 64];   // 32 KB
    const int t = threadIdx.x;

    if (blockIdx.x < GEMM0_GRID) {
        // ---- gemm0 branch: DIN=128, DOUT=64, no X staging (r13-verified) ----
        constexpr int DIN = 128, DOUT = 64, COLG = 16;
        float* Wl = smem;
        for (int i = t; i < DIN * DOUT / 4; i += 256)
            ((float4*)Wl)[i] = ((const float4*)W)[i];
        __syncthreads();

        const int row0b = blockIdx.x * 64;
        const int tx = t % COLG;
        const int ty = t / COLG;
        const int r0 = ty * 4;
        const int c0 = tx * 4;

        const float* Xr[4];
#pragma unroll
        for (int i = 0; i < 4; ++i) {
            int gr = row0b + r0 + i;
            Xr[i] = X + (size_t)min(gr, N_NODES - 1) * DIN;
        }

        float acc[4][4] = {};
#pragma unroll 4
        for (int kk = 0; kk < DIN; kk += 4) {
            float a[4][4], w[4][4];
#pragma unroll
            for (int i = 0; i < 4; ++i)
                *(float4*)a[i] = *(const float4*)&Xr[i][kk];
#pragma unroll
            for (int j = 0; j < 4; ++j)
                *(float4*)w[j] = *(const float4*)&Wl[(kk + j) * DOUT + c0];
#pragma unroll
            for (int i = 0; i < 4; ++i)
#pragma unroll
                for (int j = 0; j < 4; ++j)
                    acc[i][j] = fmaf(a[i][0], w[0][j],
                                fmaf(a[i][1], w[1][j],
                                fmaf(a[i][2], w[2][j],
                                fmaf(a[i][3], w[3][j], acc[i][j]))));
        }

        float as4[4], ad4[4];
        *(float4*)as4 = *(const float4*)&a_s[c0];
        *(float4*)ad4 = *(const float4*)&a_d[c0];

#pragma unroll
        for (int i = 0; i < 4; ++i) {
            const int gr = row0b + r0 + i;
            float ps = acc[i][0] * as4[0] + acc[i][1] * as4[1] +
                       acc[i][2] * as4[2] + acc[i][3] * as4[3];
            float pd = acc[i][0] * ad4[0] + acc[i][1] * ad4[1] +
                       acc[i][2] * ad4[2] + acc[i][3] * ad4[3];
#pragma unroll
            for (int off = COLG / 2; off >= 1; off >>= 1) {
                ps += __shfl_xor(ps, off, 64);
                pd += __shfl_xor(pd, off, 64);
            }
            if (gr < N_NODES) {
                __half2 p01 = __floats2half2_rn(acc[i][0], acc[i][1]);
                __half2 p23 = __floats2half2_rn(acc[i][2], acc[i][3]);
                uint2 pk;
                pk.x = *(unsigned int*)&p01;
                pk.y = *(unsigned int*)&p23;
                *(uint2*)&H16[gr * DOUT + c0] = pk;
                if (tx == 0) { asrc[gr] = ps; adst[gr] = pd; }
            }
        }
    } else {
        // ---- binscatter branch (r12-verified logic, uniform 256-wide scan) ----
        int* lcnt  = (int*)smem;           // [128]
        int* lbase = lcnt + 128;           // [128]
        int* lscan = lbase + 128;          // [256]

        const int v = (t < NBUCK) ? bcnt[t] : 0;
        lscan[t] = v;
        __syncthreads();
        for (int off = 1; off < 256; off <<= 1) {
            int u = (t >= off) ? lscan[t - off] : 0;
            __syncthreads();
            lscan[t] += u;
            __syncthreads();
        }
        if (t < NBUCK) lbase[t] = lscan[t] - v;
        for (int i = t; i < NBUCK; i += 256) lcnt[i] = 0;
        __syncthreads();

        const int e0 = (blockIdx.x - GEMM0_GRID) * BS_EPB;
        unsigned int pk[BS_EPT];
        int rk[BS_EPT];
        int bk[BS_EPT];
#pragma unroll
        for (int k = 0; k < BS_EPT; ++k) {
            const int eid = e0 + k * BS_THREADS + t;
            bk[k] = -1;
            if (eid < ETOT) {
                int src, dst;
                if (eid < E_EDGES) { src = ei[eid]; dst = ei[E_EDGES + eid]; }
                else               { src = dst = eid - E_EDGES; }
                bk[k] = dst >> BUCK_SHIFT;
                pk[k] = ((unsigned int)dst << 16) | (unsigned int)src;
                rk[k] = atomicAdd(&lcnt[bk[k]], 1);
            }
        }
        __syncthreads();
        for (int i = t; i < NBUCK; i += 256)
            if (lcnt[i] > 0) lbase[i] += atomicAdd(&cur[i], lcnt[i]);
        __syncthreads();
#pragma unroll
        for (int k = 0; k < BS_EPT; ++k)
            if (bk[k] >= 0) tmp[lbase[bk[k]] + rk[k]] = pk[k];
    }
}

// ---------------------------------------------------------------------------
// bucket_sort with LOCAL scan of bcnt (r12-verified).
// ---------------------------------------------------------------------------
__global__ __launch_bounds__(BUCK_SZ)
void bucket_sort_kernel(const unsigned int* __restrict__ tmp,
                        const int* __restrict__ bcnt,
                        unsigned int* __restrict__ csr_pk,
                        int* __restrict__ offs)
{
    __shared__ int lcnt[BUCK_SZ];
    __shared__ int loff[BUCK_SZ];
    __shared__ int lcur[BUCK_SZ];
    __shared__ int sbase;
    const int bk = blockIdx.x;
    const int t  = threadIdx.x;

    {
        const int v = (t < NBUCK) ? bcnt[t] : 0;
        lcnt[t] = v;
        __syncthreads();
        for (int off = 1; off < 128; off <<= 1) {
            int u = (t >= off && t < 128) ? lcnt[t - off] : 0;
            __syncthreads();
            if (t < 128) lcnt[t] += u;
            __syncthreads();
        }
        if (t == bk) sbase = lcnt[t] - v;
    }
    __syncthreads();
    const int base = sbase;
    const int cnt  = bcnt[bk];

    lcnt[t] = 0;
    __syncthreads();
    for (int i = t; i < cnt; i += BUCK_SZ)
        atomicAdd(&lcnt[(tmp[base + i] >> 16) & (BUCK_SZ - 1)], 1);
    __syncthreads();

    const int v = lcnt[t];
    loff[t] = v;
    __syncthreads();
    for (int off = 1; off < BUCK_SZ; off <<= 1) {
        int u = (t >= off) ? loff[t - off] : 0;
        __syncthreads();
        loff[t] += u;
        __syncthreads();
    }
    const int excl = loff[t] - v;

    const int g = (bk << BUCK_SHIFT) + t;
    if (g <= N_NODES) offs[g] = base + excl;   // tail node writes offs[N]=ETOT

    lcur[t] = excl;
    __syncthreads();
    for (int i = t; i < cnt; i += BUCK_SZ) {
        const unsigned int pk = tmp[base + i];
        const int l = (pk >> 16) & (BUCK_SZ - 1);
        const int pos = atomicAdd(&lcur[l], 1);
        csr_pk[base + pos] = pk;
    }
}

// ---------------------------------------------------------------------------
// Generic GEMM + alpha (layers 1,2) — no X staging, W in LDS (r13-verified).
// ---------------------------------------------------------------------------
template<int DIN, int DOUT>
__global__ __launch_bounds__(256)
void gemm_alpha_kernel(const float* __restrict__ X, const float* __restrict__ W,
                       const float* __restrict__ a_s, const float* __restrict__ a_d,
                       __half* __restrict__ H16, float* __restrict__ asrc,
                       float* __restrict__ adst)
{
    constexpr int COLG = DOUT / 4;
    constexpr int ROWG = 256 / COLG;
    constexpr int BM   = ROWG * 4;

    __shared__ float Wl[DIN * DOUT];

    const int tid = threadIdx.x;
    const int row0b = blockIdx.x * BM;

    for (int i = tid; i < DIN * DOUT / 4; i += 256)
        ((float4*)Wl)[i] = ((const float4*)W)[i];
    __syncthreads();

    const int tx = tid % COLG;
    const int ty = tid / COLG;
    const int r0 = ty * 4;
    const int c0 = tx * 4;

    const float* Xr[4];
#pragma unroll
    for (int i = 0; i < 4; ++i) {
        int gr = row0b + r0 + i;
        Xr[i] = X + (size_t)min(gr, N_NODES - 1) * DIN;
    }

    float acc[4][4] = {};
#pragma unroll 4
    for (int kk = 0; kk < DIN; kk += 4) {
        float a[4][4], w[4][4];
#pragma unroll
        for (int i = 0; i < 4; ++i)
            *(float4*)a[i] = *(const float4*)&Xr[i][kk];
#pragma unroll
        for (int j = 0; j < 4; ++j)
            *(float4*)w[j] = *(const float4*)&Wl[(kk + j) * DOUT + c0];
#pragma unroll
        for (int i = 0; i < 4; ++i)
#pragma unroll
            for (int j = 0; j < 4; ++j)
                acc[i][j] = fmaf(a[i][0], w[0][j],
                            fmaf(a[i][1], w[1][j],
                            fmaf(a[i][2], w[2][j],
                            fmaf(a[i][3], w[3][j], acc[i][j]))));
    }

    float as4[4], ad4[4];
    *(float4*)as4 = *(const float4*)&a_s[c0];
    *(float4*)ad4 = *(const float4*)&a_d[c0];

#pragma unroll
    for (int i = 0; i < 4; ++i) {
        const int gr = row0b + r0 + i;
        float ps = acc[i][0] * as4[0] + acc[i][1] * as4[1] +
                   acc[i][2] * as4[2] + acc[i][3] * as4[3];
        float pd = acc[i][0] * ad4[0] + acc[i][1] * ad4[1] +
                   acc[i][2] * ad4[2] + acc[i][3] * ad4[3];
#pragma unroll
        for (int off = COLG / 2; off >= 1; off >>= 1) {
            ps += __shfl_xor(ps, off, 64);
            pd += __shfl_xor(pd, off, 64);
        }
        if (gr < N_NODES) {
            __half2 p01 = __floats2half2_rn(acc[i][0], acc[i][1]);
            __half2 p23 = __floats2half2_rn(acc[i][2], acc[i][3]);
            uint2 pk;
            pk.x = *(unsigned int*)&p01;
            pk.y = *(unsigned int*)&p23;
            *(uint2*)&H16[gr * DOUT + c0] = pk;
            if (tx == 0) { asrc[gr] = ps; adst[gr] = pd; }
        }
    }
}

// ---------------------------------------------------------------------------
// node_agg v5 (verified): inline score, 16B fp16 gathers, pk prefetch.
// ---------------------------------------------------------------------------
template<int DOUT, int ACT>
__global__ __launch_bounds__(256)
void node_agg_kernel(const int* __restrict__ offs,
                     const unsigned int* __restrict__ csr_pk,
                     const float* __restrict__ asrc,
                     const float* __restrict__ adst,
                     const __half* __restrict__ H16,
                     const float* __restrict__ b,
                     float* __restrict__ out)
{
    constexpr int FL    = DOUT / 8;    // 8 (dout=64) or 4 (dout=32)
    constexpr int SLOTS = 64 / FL;     // 8 or 16
    const int wv   = threadIdx.x >> 6;
    const int lane = threadIdx.x & 63;
    const int fl   = lane % FL;
    const int slot = lane / FL;
    const int node = blockIdx.x * 4 + wv;
    if (node >= N_NODES) return;

    const int beg = offs[node];
    const int end = offs[node + 1];
    const float adn = adst[node];
    const __half* __restrict__ Hf = H16 + fl * 8;

    float s = 0.f;
    float acc[8] = {};

    int eid = beg + slot;
    bool valid = (eid < end);
    unsigned int pk = valid ? csr_pk[eid] : 0u;

    for (int cb = beg; cb < end; cb += SLOTS) {
        const int nid = cb + SLOTS + slot;
        const bool nvalid = (nid < end);
        const unsigned int npk = nvalid ? csr_pk[nid] : 0u;

        float p = 0.f;
        uint4 h = make_uint4(0u, 0u, 0u, 0u);
        if (valid) {
            const unsigned int src = pk & 0xffffu;
            float v = asrc[src] + adn;
            v = fmaxf(v, 0.2f * v);
            p = __expf(fminf(v, 80.f));
            h = *(const uint4*)(Hf + src * DOUT);
        }
        const float2 f0 = __half22float2(*(const __half2*)&h.x);
        const float2 f1 = __half22float2(*(const __half2*)&h.y);
        const float2 f2 = __half22float2(*(const __half2*)&h.z);
        const float2 f3 = __half22float2(*(const __half2*)&h.w);
        s += p;
        acc[0] = fmaf(p, f0.x, acc[0]);
        acc[1] = fmaf(p, f0.y, acc[1]);
        acc[2] = fmaf(p, f1.x, acc[2]);
        acc[3] = fmaf(p, f1.y, acc[3]);
        acc[4] = fmaf(p, f2.x, acc[4]);
        acc[5] = fmaf(p, f2.y, acc[5]);
        acc[6] = fmaf(p, f3.x, acc[6]);
        acc[7] = fmaf(p, f3.y, acc[7]);
        valid = nvalid;
        pk = npk;
    }

#pragma unroll
    for (int off = FL; off < 64; off <<= 1) {
        s += __shfl_xor(s, off, 64);
#pragma unroll
        for (int j = 0; j < 8; ++j)
            acc[j] += __shfl_xor(acc[j], off, 64);
    }

    if (slot == 0) {
        const float inv = 1.f / s;
        float o[8];
#pragma unroll
        for (int j = 0; j < 8; ++j) {
            float v = acc[j] * inv + b[fl * 8 + j];
            o[j] = (ACT == 0) ? fmaxf(v, 0.f) : tanhf(v);
        }
        *(float4*)&out[node * DOUT + fl * 8]     = *(float4*)&o[0];
        *(float4*)&out[node * DOUT + fl * 8 + 4] = *(float4*)&o[4];
    }
}

// ---------------------------------------------------------------------------

extern "C" void kernel_launch(void* const* d_in, const int* in_sizes, int n_in,
                              void* d_out, int out_size, void* d_ws, size_t ws_size,
                              hipStream_t stream)
{
    const float* x  = (const float*)d_in[0];
    const int*   ei = (const int*)d_in[1];
    const float* W0 = (const float*)d_in[2];
    const float* as0= (const float*)d_in[3];
    const float* ad0= (const float*)d_in[4];
    const float* b0 = (const float*)d_in[5];
    const float* W1 = (const float*)d_in[6];
    const float* as1= (const float*)d_in[7];
    const float* ad1= (const float*)d_in[8];
    const float* b1 = (const float*)d_in[9];
    const float* W2 = (const float*)d_in[10];
    const float* as2= (const float*)d_in[11];
    const float* ad2= (const float*)d_in[12];
    const float* b2 = (const float*)d_in[13];
    float* out = (float*)d_out;

    char* wsb = (char*)d_ws;
    auto take = [&](size_t bytes) {
        char* p = wsb;
        wsb += (bytes + 255) & ~size_t(255);
        return p;
    };
    __half* h16    = (__half*)take(sizeof(__half) * N_NODES * 64);
    float* buf_act = (float*)take(sizeof(float) * N_NODES * 64);
    float* asrc    = (float*)take(sizeof(float) * N_NODES);
    float* adst    = (float*)take(sizeof(float) * N_NODES);
    int*   offs    = (int*)take(sizeof(int) * (N_NODES + 1));
    int*   bc      = (int*)take(sizeof(int) * NBUCK * 2);   // bcnt | cur
    int*   bcnt    = bc;
    int*   cur     = bc + NBUCK;
    // tmp must NOT alias h16 now: binscatter writes tmp concurrently with
    // gemm0 writing h16 in the packed dispatch.
    unsigned int* tmp    = (unsigned int*)take(sizeof(unsigned int) * ETOT);
    unsigned int* csr_pk = (unsigned int*)take(sizeof(unsigned int) * ETOT);

    hipMemsetAsync(bc, 0, sizeof(int) * NBUCK * 2, stream);

    // bucket histogram (needs only ei)
    hist_kernel<<<BS_NBLK, BS_THREADS, 0, stream>>>(ei, bcnt);

    // gemm0 and binscatter are independent -> one packed dispatch,
    // each phase at its natural grid
    gemm0_binscatter_kernel<<<PACK_GRID, 256, 0, stream>>>(
        x, W0, as0, ad0, h16, asrc, adst, ei, bcnt, cur, tmp);

    bucket_sort_kernel<<<NBUCK, BUCK_SZ, 0, stream>>>(tmp, bcnt, csr_pk, offs);

    const int agg_grid = (N_NODES + 3) / 4;
    node_agg_kernel<64, 0><<<agg_grid, 256, 0, stream>>>(
        offs, csr_pk, asrc, adst, h16, b0, buf_act);

    gemm_alpha_kernel<64, 64><<<GEMM0_GRID, 256, 0, stream>>>(
        buf_act, W1, as1, ad1, h16, asrc, adst);
    node_agg_kernel<64, 0><<<agg_grid, 256, 0, stream>>>(
        offs, csr_pk, asrc, adst, h16, b1, buf_act);

    gemm_alpha_kernel<64, 32><<<(N_NODES + 127) / 128, 256, 0, stream>>>(
        buf_act, W2, as2, ad2, h16, asrc, adst);
    node_agg_kernel<32, 1><<<agg_grid, 256, 0, stream>>>(
        offs, csr_pk, asrc, adst, h16, b2, out);
}

// Round 17
// 164.071 us; speedup vs baseline: 6.5294x; 1.0511x over previous
//
#include <hip/hip_runtime.h>
#include <hip/hip_fp16.h>
#include <math.h>

#define N_NODES 50000
#define E_EDGES 800000
#define ETOT    (E_EDGES + N_NODES)

// bucketed scatter params
#define BUCK_SHIFT 9
#define BUCK_SZ   (1 << BUCK_SHIFT)                               // 512
#define NBUCK ((N_NODES + BUCK_SZ - 1) >> BUCK_SHIFT)             // 98
#define BS_EPT 16
#define BS_THREADS 256
#define BS_EPB (BS_THREADS * BS_EPT)                              // 4096
#define BS_NBLK ((ETOT + BS_EPB - 1) / BS_EPB)                    // 208

// fixed-capacity bucket slots in tmp (mean count 8704, sd ~90)
#define CAP_SHIFT 14
#define CAP (1 << CAP_SHIFT)                                      // 16384

#define GEMM0_GRID ((N_NODES + 63) / 64)                          // 782
#define PACK_GRID (GEMM0_GRID + BS_NBLK)                          // 990

// ---------------------------------------------------------------------------
// PACKED: gemm0 (blocks 0..781) || binscatter (blocks 782..989).
// binscatter now needs NO histogram: fixed-capacity slots, cur[] zeroed.
// After this kernel, cur[bk] == bucket bk's edge count.
// ---------------------------------------------------------------------------
__global__ __launch_bounds__(256)
void gemm0_binscatter_kernel(const float* __restrict__ X,
                             const float* __restrict__ W,
                             const float* __restrict__ a_s,
                             const float* __restrict__ a_d,
                             __half* __restrict__ H16,
                             float* __restrict__ asrc,
                             float* __restrict__ adst,
                             const int* __restrict__ ei,
                             int* __restrict__ cur,
                             unsigned int* __restrict__ tmp)
{
    __shared__ float smem[128 * 64];   // 32 KB
    const int t = threadIdx.x;

    if (blockIdx.x < GEMM0_GRID) {
        // ---- gemm0 branch: DIN=128, DOUT=64, no X staging (r13-verified) ----
        constexpr int DIN = 128, DOUT = 64, COLG = 16;
        float* Wl = smem;
        for (int i = t; i < DIN * DOUT / 4; i += 256)
            ((float4*)Wl)[i] = ((const float4*)W)[i];
        __syncthreads();

        const int row0b = blockIdx.x * 64;
        const int tx = t % COLG;
        const int ty = t / COLG;
        const int r0 = ty * 4;
        const int c0 = tx * 4;

        const float* Xr[4];
#pragma unroll
        for (int i = 0; i < 4; ++i) {
            int gr = row0b + r0 + i;
            Xr[i] = X + (size_t)min(gr, N_NODES - 1) * DIN;
        }

        float acc[4][4] = {};
#pragma unroll 4
        for (int kk = 0; kk < DIN; kk += 4) {
            float a[4][4], w[4][4];
#pragma unroll
            for (int i = 0; i < 4; ++i)
                *(float4*)a[i] = *(const float4*)&Xr[i][kk];
#pragma unroll
            for (int j = 0; j < 4; ++j)
                *(float4*)w[j] = *(const float4*)&Wl[(kk + j) * DOUT + c0];
#pragma unroll
            for (int i = 0; i < 4; ++i)
#pragma unroll
                for (int j = 0; j < 4; ++j)
                    acc[i][j] = fmaf(a[i][0], w[0][j],
                                fmaf(a[i][1], w[1][j],
                                fmaf(a[i][2], w[2][j],
                                fmaf(a[i][3], w[3][j], acc[i][j]))));
        }

        float as4[4], ad4[4];
        *(float4*)as4 = *(const float4*)&a_s[c0];
        *(float4*)ad4 = *(const float4*)&a_d[c0];

#pragma unroll
        for (int i = 0; i < 4; ++i) {
            const int gr = row0b + r0 + i;
            float ps = acc[i][0] * as4[0] + acc[i][1] * as4[1] +
                       acc[i][2] * as4[2] + acc[i][3] * as4[3];
            float pd = acc[i][0] * ad4[0] + acc[i][1] * ad4[1] +
                       acc[i][2] * ad4[2] + acc[i][3] * ad4[3];
#pragma unroll
            for (int off = COLG / 2; off >= 1; off >>= 1) {
                ps += __shfl_xor(ps, off, 64);
                pd += __shfl_xor(pd, off, 64);
            }
            if (gr < N_NODES) {
                __half2 p01 = __floats2half2_rn(acc[i][0], acc[i][1]);
                __half2 p23 = __floats2half2_rn(acc[i][2], acc[i][3]);
                uint2 pk;
                pk.x = *(unsigned int*)&p01;
                pk.y = *(unsigned int*)&p23;
                *(uint2*)&H16[gr * DOUT + c0] = pk;
                if (tx == 0) { asrc[gr] = ps; adst[gr] = pd; }
            }
        }
    } else {
        // ---- binscatter branch: fixed-capacity slots, no scan needed ----
        int* lcnt  = (int*)smem;           // [NBUCK]
        int* lbase = lcnt + 128;           // [NBUCK]

        for (int i = t; i < NBUCK; i += 256) lcnt[i] = 0;
        __syncthreads();

        const int e0 = (blockIdx.x - GEMM0_GRID) * BS_EPB;
        unsigned int pk[BS_EPT];
        int rk[BS_EPT];
        int bk[BS_EPT];
#pragma unroll
        for (int k = 0; k < BS_EPT; ++k) {
            const int eid = e0 + k * BS_THREADS + t;
            bk[k] = -1;
            if (eid < ETOT) {
                int src, dst;
                if (eid < E_EDGES) { src = ei[eid]; dst = ei[E_EDGES + eid]; }
                else               { src = dst = eid - E_EDGES; }
                bk[k] = dst >> BUCK_SHIFT;
                pk[k] = ((unsigned int)dst << 16) | (unsigned int)src;
                rk[k] = atomicAdd(&lcnt[bk[k]], 1);
            }
        }
        __syncthreads();
        for (int i = t; i < NBUCK; i += 256)
            if (lcnt[i] > 0)
                lbase[i] = (i << CAP_SHIFT) + atomicAdd(&cur[i], lcnt[i]);
        __syncthreads();
#pragma unroll
        for (int k = 0; k < BS_EPT; ++k)
            if (bk[k] >= 0) tmp[lbase[bk[k]] + rk[k]] = pk[k];
    }
}

// ---------------------------------------------------------------------------
// bucket_sort: reads tmp at fixed-stride base, counts from cur (filled by
// binscatter), csr base via local scan of cur. Emits csr_pk + offs.
// ---------------------------------------------------------------------------
__global__ __launch_bounds__(BUCK_SZ)
void bucket_sort_kernel(const unsigned int* __restrict__ tmp,
                        const int* __restrict__ cur,
                        unsigned int* __restrict__ csr_pk,
                        int* __restrict__ offs)
{
    __shared__ int lcnt[BUCK_SZ];
    __shared__ int loff[BUCK_SZ];
    __shared__ int lcur[BUCK_SZ];
    __shared__ int sbase;
    const int bk = blockIdx.x;
    const int t  = threadIdx.x;

    // csr base = exclusive prefix of cur[] at bk (local 128-wide scan)
    {
        const int v = (t < NBUCK) ? cur[t] : 0;
        lcnt[t] = v;
        __syncthreads();
        for (int off = 1; off < 128; off <<= 1) {
            int u = (t >= off && t < 128) ? lcnt[t - off] : 0;
            __syncthreads();
            if (t < 128) lcnt[t] += u;
            __syncthreads();
        }
        if (t == bk) sbase = lcnt[t] - v;
    }
    __syncthreads();
    const int base  = sbase;                 // csr base
    const int tbase = bk << CAP_SHIFT;       // tmp base
    const int cnt   = cur[bk];

    lcnt[t] = 0;
    __syncthreads();
    for (int i = t; i < cnt; i += BUCK_SZ)
        atomicAdd(&lcnt[(tmp[tbase + i] >> 16) & (BUCK_SZ - 1)], 1);
    __syncthreads();

    const int v = lcnt[t];
    loff[t] = v;
    __syncthreads();
    for (int off = 1; off < BUCK_SZ; off <<= 1) {
        int u = (t >= off) ? loff[t - off] : 0;
        __syncthreads();
        loff[t] += u;
        __syncthreads();
    }
    const int excl = loff[t] - v;

    const int g = (bk << BUCK_SHIFT) + t;
    if (g <= N_NODES) offs[g] = base + excl;   // tail node writes offs[N]=ETOT

    lcur[t] = excl;
    __syncthreads();
    for (int i = t; i < cnt; i += BUCK_SZ) {
        const unsigned int pk = tmp[tbase + i];
        const int l = (pk >> 16) & (BUCK_SZ - 1);
        const int pos = atomicAdd(&lcur[l], 1);
        csr_pk[base + pos] = pk;
    }
}

// ---------------------------------------------------------------------------
// Generic GEMM + alpha (layers 1,2) — no X staging, W in LDS (r13-verified).
// ---------------------------------------------------------------------------
template<int DIN, int DOUT>
__global__ __launch_bounds__(256)
void gemm_alpha_kernel(const float* __restrict__ X, const float* __restrict__ W,
                       const float* __restrict__ a_s, const float* __restrict__ a_d,
                       __half* __restrict__ H16, float* __restrict__ asrc,
                       float* __restrict__ adst)
{
    constexpr int COLG = DOUT / 4;
    constexpr int ROWG = 256 / COLG;
    constexpr int BM   = ROWG * 4;

    __shared__ float Wl[DIN * DOUT];

    const int tid = threadIdx.x;
    const int row0b = blockIdx.x * BM;

    for (int i = tid; i < DIN * DOUT / 4; i += 256)
        ((float4*)Wl)[i] = ((const float4*)W)[i];
    __syncthreads();

    const int tx = tid % COLG;
    const int ty = tid / COLG;
    const int r0 = ty * 4;
    const int c0 = tx * 4;

    const float* Xr[4];
#pragma unroll
    for (int i = 0; i < 4; ++i) {
        int gr = row0b + r0 + i;
        Xr[i] = X + (size_t)min(gr, N_NODES - 1) * DIN;
    }

    float acc[4][4] = {};
#pragma unroll 4
    for (int kk = 0; kk < DIN; kk += 4) {
        float a[4][4], w[4][4];
#pragma unroll
        for (int i = 0; i < 4; ++i)
            *(float4*)a[i] = *(const float4*)&Xr[i][kk];
#pragma unroll
        for (int j = 0; j < 4; ++j)
            *(float4*)w[j] = *(const float4*)&Wl[(kk + j) * DOUT + c0];
#pragma unroll
        for (int i = 0; i < 4; ++i)
#pragma unroll
            for (int j = 0; j < 4; ++j)
                acc[i][j] = fmaf(a[i][0], w[0][j],
                            fmaf(a[i][1], w[1][j],
                            fmaf(a[i][2], w[2][j],
                            fmaf(a[i][3], w[3][j], acc[i][j]))));
    }

    float as4[4], ad4[4];
    *(float4*)as4 = *(const float4*)&a_s[c0];
    *(float4*)ad4 = *(const float4*)&a_d[c0];

#pragma unroll
    for (int i = 0; i < 4; ++i) {
        const int gr = row0b + r0 + i;
        float ps = acc[i][0] * as4[0] + acc[i][1] * as4[1] +
                   acc[i][2] * as4[2] + acc[i][3] * as4[3];
        float pd = acc[i][0] * ad4[0] + acc[i][1] * ad4[1] +
                   acc[i][2] * ad4[2] + acc[i][3] * ad4[3];
#pragma unroll
        for (int off = COLG / 2; off >= 1; off >>= 1) {
            ps += __shfl_xor(ps, off, 64);
            pd += __shfl_xor(pd, off, 64);
        }
        if (gr < N_NODES) {
            __half2 p01 = __floats2half2_rn(acc[i][0], acc[i][1]);
            __half2 p23 = __floats2half2_rn(acc[i][2], acc[i][3]);
            uint2 pk;
            pk.x = *(unsigned int*)&p01;
            pk.y = *(unsigned int*)&p23;
            *(uint2*)&H16[gr * DOUT + c0] = pk;
            if (tx == 0) { asrc[gr] = ps; adst[gr] = pd; }
        }
    }
}

// ---------------------------------------------------------------------------
// node_agg v5 (verified): inline score, 16B fp16 gathers, pk prefetch.
// ---------------------------------------------------------------------------
template<int DOUT, int ACT>
__global__ __launch_bounds__(256)
void node_agg_kernel(const int* __restrict__ offs,
                     const unsigned int* __restrict__ csr_pk,
                     const float* __restrict__ asrc,
                     const float* __restrict__ adst,
                     const __half* __restrict__ H16,
                     const float* __restrict__ b,
                     float* __restrict__ out)
{
    constexpr int FL    = DOUT / 8;    // 8 (dout=64) or 4 (dout=32)
    constexpr int SLOTS = 64 / FL;     // 8 or 16
    const int wv   = threadIdx.x >> 6;
    const int lane = threadIdx.x & 63;
    const int fl   = lane % FL;
    const int slot = lane / FL;
    const int node = blockIdx.x * 4 + wv;
    if (node >= N_NODES) return;

    const int beg = offs[node];
    const int end = offs[node + 1];
    const float adn = adst[node];
    const __half* __restrict__ Hf = H16 + fl * 8;

    float s = 0.f;
    float acc[8] = {};

    int eid = beg + slot;
    bool valid = (eid < end);
    unsigned int pk = valid ? csr_pk[eid] : 0u;

    for (int cb = beg; cb < end; cb += SLOTS) {
        const int nid = cb + SLOTS + slot;
        const bool nvalid = (nid < end);
        const unsigned int npk = nvalid ? csr_pk[nid] : 0u;

        float p = 0.f;
        uint4 h = make_uint4(0u, 0u, 0u, 0u);
        if (valid) {
            const unsigned int src = pk & 0xffffu;
            float v = asrc[src] + adn;
            v = fmaxf(v, 0.2f * v);
            p = __expf(fminf(v, 80.f));
            h = *(const uint4*)(Hf + src * DOUT);
        }
        const float2 f0 = __half22float2(*(const __half2*)&h.x);
        const float2 f1 = __half22float2(*(const __half2*)&h.y);
        const float2 f2 = __half22float2(*(const __half2*)&h.z);
        const float2 f3 = __half22float2(*(const __half2*)&h.w);
        s += p;
        acc[0] = fmaf(p, f0.x, acc[0]);
        acc[1] = fmaf(p, f0.y, acc[1]);
        acc[2] = fmaf(p, f1.x, acc[2]);
        acc[3] = fmaf(p, f1.y, acc[3]);
        acc[4] = fmaf(p, f2.x, acc[4]);
        acc[5] = fmaf(p, f2.y, acc[5]);
        acc[6] = fmaf(p, f3.x, acc[6]);
        acc[7] = fmaf(p, f3.y, acc[7]);
        valid = nvalid;
        pk = npk;
    }

#pragma unroll
    for (int off = FL; off < 64; off <<= 1) {
        s += __shfl_xor(s, off, 64);
#pragma unroll
        for (int j = 0; j < 8; ++j)
            acc[j] += __shfl_xor(acc[j], off, 64);
    }

    if (slot == 0) {
        const float inv = 1.f / s;
        float o[8];
#pragma unroll
        for (int j = 0; j < 8; ++j) {
            float v = acc[j] * inv + b[fl * 8 + j];
            o[j] = (ACT == 0) ? fmaxf(v, 0.f) : tanhf(v);
        }
        *(float4*)&out[node * DOUT + fl * 8]     = *(float4*)&o[0];
        *(float4*)&out[node * DOUT + fl * 8 + 4] = *(float4*)&o[4];
    }
}

// ---------------------------------------------------------------------------

extern "C" void kernel_launch(void* const* d_in, const int* in_sizes, int n_in,
                              void* d_out, int out_size, void* d_ws, size_t ws_size,
                              hipStream_t stream)
{
    const float* x  = (const float*)d_in[0];
    const int*   ei = (const int*)d_in[1];
    const float* W0 = (const float*)d_in[2];
    const float* as0= (const float*)d_in[3];
    const float* ad0= (const float*)d_in[4];
    const float* b0 = (const float*)d_in[5];
    const float* W1 = (const float*)d_in[6];
    const float* as1= (const float*)d_in[7];
    const float* ad1= (const float*)d_in[8];
    const float* b1 = (const float*)d_in[9];
    const float* W2 = (const float*)d_in[10];
    const float* as2= (const float*)d_in[11];
    const float* ad2= (const float*)d_in[12];
    const float* b2 = (const float*)d_in[13];
    float* out = (float*)d_out;

    char* wsb = (char*)d_ws;
    auto take = [&](size_t bytes) {
        char* p = wsb;
        wsb += (bytes + 255) & ~size_t(255);
        return p;
    };
    __half* h16    = (__half*)take(sizeof(__half) * N_NODES * 64);
    float* buf_act = (float*)take(sizeof(float) * N_NODES * 64);
    float* asrc    = (float*)take(sizeof(float) * N_NODES);
    float* adst    = (float*)take(sizeof(float) * N_NODES);
    int*   offs    = (int*)take(sizeof(int) * (N_NODES + 1));
    int*   cur     = (int*)take(sizeof(int) * NBUCK);
    unsigned int* tmp    = (unsigned int*)take(sizeof(unsigned int) * NBUCK * CAP);
    unsigned int* csr_pk = (unsigned int*)take(sizeof(unsigned int) * ETOT);

    hipMemsetAsync(cur, 0, sizeof(int) * NBUCK, stream);

    // gemm0 and binscatter are independent -> one packed dispatch
    gemm0_binscatter_kernel<<<PACK_GRID, 256, 0, stream>>>(
        x, W0, as0, ad0, h16, asrc, adst, ei, cur, tmp);

    bucket_sort_kernel<<<NBUCK, BUCK_SZ, 0, stream>>>(tmp, cur, csr_pk, offs);

    const int agg_grid = (N_NODES + 3) / 4;
    node_agg_kernel<64, 0><<<agg_grid, 256, 0, stream>>>(
        offs, csr_pk, asrc, adst, h16, b0, buf_act);

    gemm_alpha_kernel<64, 64><<<GEMM0_GRID, 256, 0, stream>>>(
        buf_act, W1, as1, ad1, h16, asrc, adst);
    node_agg_kernel<64, 0><<<agg_grid, 256, 0, stream>>>(
        offs, csr_pk, asrc, adst, h16, b1, buf_act);

    gemm_alpha_kernel<64, 32><<<(N_NODES + 127) / 128, 256, 0, stream>>>(
        buf_act, W2, as2, ad2, h16, asrc, adst);
    node_agg_kernel<32, 1><<<agg_grid, 256, 0, stream>>>(
        offs, csr_pk, asrc, adst, h16, b2, out);
}